// Round 7
// baseline (4415.152 us; speedup 1.0000x reference)
//
#include <hip/hip_runtime.h>
#include <hip/hip_cooperative_groups.h>
#include <cstddef>
#include <cstdint>
#include <math.h>

#define BB 64
#define PP 196
#define ENCD 512
#define DECD 512
#define ATTD 512
#define VOC 10000
#define CLSE 512
#define MAXLEN 52
#define MAXT 51
#define G4 2048
#define XDIM 1536

// ---- d_out offsets (float elements) ----
#define OFF_PRED 0
#define OFF_CAPS (BB * MAXT * VOC)
#define OFF_DECLEN (OFF_CAPS + BB * MAXLEN)
#define OFF_SORT (OFF_DECLEN + BB)

// ---- workspace offsets (4-byte units) ----
static constexpr size_t W_SORT   = 0;
static constexpr size_t W_DECLEN = 64;
static constexpr size_t W_CAPS   = 128;                       // int[64*52] -> 3456
static constexpr size_t W_CNTP   = 3456;                      // int[51*64]
static constexpr size_t W_CNTX   = W_CNTP + 3264;             // int[51*64]
static constexpr size_t W_AWEF   = W_CNTX + 3264;             // int[64]
static constexpr size_t W_HFLG   = W_AWEF + 64;               // int[256]
static constexpr size_t W_CLS    = W_HFLG + 256;              // 10304
static constexpr size_t W_H      = W_CLS + BB * CLSE;         // h ping
static constexpr size_t W_H2     = W_H + BB * DECD;           // h pong
static constexpr size_t W_C      = W_H2 + BB * DECD;
static constexpr size_t W_ININ   = W_C + BB * DECD;
static constexpr size_t W_EXCH   = W_ININ + BB * 1024;        // f32[64*1024] att2|fg
static constexpr size_t W_AWE    = W_EXCH + BB * 1024;
static constexpr size_t W_CLSPRE = W_AWE + BB * ENCD;
static constexpr size_t W_W3P    = W_CLSPRE + BB * G4;        // f32[256*8*512]
static constexpr size_t W_W2P    = W_W3P + (size_t)256 * 8 * 512;    // f32[256*8*1024]
static constexpr size_t W_HALL   = W_W2P + (size_t)256 * 8 * 1024;   // f32[64*51*512]
static constexpr size_t W_ATT1   = W_HALL + (size_t)BB * MAXT * DECD;
static constexpr size_t W_PAWE   = W_ATT1 + (size_t)BB * PP * ATTD;  // f32[64*4*520]
static constexpr size_t W_CPRE2  = W_PAWE + (size_t)BB * 4 * 520;    // f32[51*64*2048]
static constexpr size_t W_END    = W_CPRE2 + (size_t)MAXT * BB * G4;

__device__ __forceinline__ float sigm(float x) { return 1.f / (1.f + expf(-x)); }

// MALL-coherent (agent-scope, RELAXED) helpers — the r4/r6-proven idiom.
__device__ __forceinline__ double cohLd(const double* p) {
    return __hip_atomic_load(p, __ATOMIC_RELAXED, __HIP_MEMORY_SCOPE_AGENT);
}
__device__ __forceinline__ float cohLdF(const float* p) {
    return __hip_atomic_load(p, __ATOMIC_RELAXED, __HIP_MEMORY_SCOPE_AGENT);
}
__device__ __forceinline__ int cohLdI(const int* p) {
    return __hip_atomic_load(p, __ATOMIC_RELAXED, __HIP_MEMORY_SCOPE_AGENT);
}
__device__ __forceinline__ void cohSt(double* p, double v) {
    __hip_atomic_store(p, v, __ATOMIC_RELAXED, __HIP_MEMORY_SCOPE_AGENT);
}
__device__ __forceinline__ void cohStF(float* p, float v) {
    __hip_atomic_store(p, v, __ATOMIC_RELAXED, __HIP_MEMORY_SCOPE_AGENT);
}
__device__ __forceinline__ void cohStI(int* p, int v) {
    __hip_atomic_store(p, v, __ATOMIC_RELAXED, __HIP_MEMORY_SCOPE_AGENT);
}

// ---------------- setup: stable descending argsort + flag/counter init ----------------
__global__ void setup_kernel(const int* __restrict__ cap_len, float* __restrict__ out,
                             int* __restrict__ sortind, int* __restrict__ declen,
                             int* __restrict__ cnt) {
    __shared__ int sl[BB];
    int i = threadIdx.x;
    for (int k = i; k < 6848; k += 64) cnt[k] = 0;   // cntP+cntX+aweflag+hflag
    sl[i] = cap_len[i];
    __syncthreads();
    int li = sl[i];
    int rank = 0;
    for (int j = 0; j < BB; j++) {
        int lj = sl[j];
        rank += (lj > li) || (lj == li && j < i);
    }
    sortind[rank] = i;
    declen[rank] = li - 1;
    out[OFF_SORT + rank] = (float)i;
    out[OFF_DECLEN + rank] = (float)(li - 1);
}

// ---------------- gather caps (sorted) + cls_emb (UNSORTED) ----------------
__global__ void gather_kernel(const int* __restrict__ ecaps, const int* __restrict__ classk,
                              const float* __restrict__ clsW, const int* __restrict__ sortind,
                              int* __restrict__ caps_i, float* __restrict__ cls,
                              float* __restrict__ out) {
    int idx = blockIdx.x * 256 + threadIdx.x;
    if (idx < BB * MAXLEN) {
        int b = idx / MAXLEN, t2 = idx - b * MAXLEN;
        int sb = sortind[b];
        int v = ecaps[sb * MAXLEN + t2];
        caps_i[idx] = v;
        out[OFF_CAPS + idx] = (float)v;
    }
    int j = idx - BB * MAXLEN;
    if (j >= 0 && j < BB * CLSE) {
        int row = j >> 9, k = j & 511;
        int ck = classk[row];
        cls[j] = clsW[ck * CLSE + k];
    }
}

// ---------------- mean over P + build init_in ----------------
__global__ void mean_cls_kernel(const float* __restrict__ enc, const float* __restrict__ cls,
                                const int* __restrict__ sortind, float* __restrict__ initin) {
    int b = blockIdx.x;
    int sb = sortind[b];
    for (int k = threadIdx.x; k < ENCD; k += 256) {
        const float* ep = enc + (size_t)sb * PP * ENCD + k;
        float s = 0.f;
        for (int p = 0; p < PP; p++) s += ep[(size_t)p * ENCD];
        initin[b * 1024 + k] = s * (1.f / 196.f);
        initin[b * 1024 + 512 + k] = cls[b * CLSE + k];
    }
}

// ---------------- h0 / c0 ----------------
__global__ void init_hc_kernel(const float* __restrict__ initin,
                               const float* __restrict__ hW, const float* __restrict__ hb,
                               const float* __restrict__ cW, const float* __restrict__ cb,
                               float* __restrict__ h, float* __restrict__ c) {
    int gid = blockIdx.x * 256 + threadIdx.x; // < 65536
    int j = gid & 511, b = (gid >> 9) & 63, which = gid >> 15;
    const float* W = which ? cW : hW;
    const float* bias = which ? cb : hb;
    const float* x = initin + b * 1024;
    float acc = bias[j];
    for (int k = 0; k < 1024; k++) acc += x[k] * W[(size_t)k * 512 + j];
    (which ? c : h)[b * 512 + j] = acc;
}

// W2p[j][cc][k], cc<8, k<1024: gate=cc>>1, dd=cc&1, gcol=512*gate+2j+dd
__global__ void pack_w2p_kernel(const float* __restrict__ wih, float* __restrict__ W2p) {
    int gid = blockIdx.x * 256 + threadIdx.x; // < 256*8*1024
    int k = gid & 1023, cc = (gid >> 10) & 7, jb = gid >> 13;
    int gcol = 512 * (cc >> 1) + 2 * jb + (cc & 1);
    W2p[gid] = wih[(size_t)gcol * XDIM + k];
}

// W3p[j][cc][k], cc<8, k<512: Whh rows for block j's 8 gate cols
__global__ void pack_w3p_kernel(const float* __restrict__ whh, float* __restrict__ W3p) {
    int gid = blockIdx.x * 256 + threadIdx.x; // < 256*8*512
    int k = gid & 511, cc = (gid >> 9) & 7, jb = gid >> 12;
    int gcol = 512 * (cc >> 1) + 2 * jb + (cc & 1);
    W3p[gid] = whh[(size_t)gcol * 512 + k];
}

// ---------------- att1 = enc_sorted @ enc_att_W + b ----------------
__global__ __launch_bounds__(256)
void att1_kernel(const float* __restrict__ enc, const float* __restrict__ Wa,
                 const float* __restrict__ ba, const int* __restrict__ sortind,
                 float* __restrict__ att1) {
    __shared__ float As[16][68];
    __shared__ float Bs[16][64];
    int tid = threadIdx.x;
    int n0 = blockIdx.x * 64, m0 = blockIdx.y * 64;
    int tx = tid & 15, ty = tid >> 4;
    int lm = tid >> 2, lk4 = (tid & 3) * 4;
    int bkk = tid >> 4, bnn4 = (tid & 15) * 4;
    int gm = m0 + lm;
    int b = gm / PP, p = gm - b * PP;
    int sb = sortind[b];
    const float* arow = enc + ((size_t)sb * PP + p) * ENCD;
    float acc[4][4] = {};
    for (int k0 = 0; k0 < ENCD; k0 += 16) {
        float4 av = *(const float4*)(arow + k0 + lk4);
        float4 bv = *(const float4*)(Wa + (size_t)(k0 + bkk) * 512 + n0 + bnn4);
        __syncthreads();
        As[lk4 + 0][lm] = av.x; As[lk4 + 1][lm] = av.y;
        As[lk4 + 2][lm] = av.z; As[lk4 + 3][lm] = av.w;
        *(float4*)&Bs[bkk][bnn4] = bv;
        __syncthreads();
#pragma unroll
        for (int kk = 0; kk < 16; kk++) {
            float4 a4 = *(const float4*)&As[kk][ty * 4];
            float4 b4 = *(const float4*)&Bs[kk][tx * 4];
            float a[4] = {a4.x, a4.y, a4.z, a4.w};
#pragma unroll
            for (int i = 0; i < 4; i++) {
                acc[i][0] = fmaf(a[i], b4.x, acc[i][0]);
                acc[i][1] = fmaf(a[i], b4.y, acc[i][1]);
                acc[i][2] = fmaf(a[i], b4.z, acc[i][2]);
                acc[i][3] = fmaf(a[i], b4.w, acc[i][3]);
            }
        }
    }
#pragma unroll
    for (int i = 0; i < 4; i++) {
        int m = m0 + ty * 4 + i;
        int n = n0 + tx * 4;
        float4 o;
        o.x = acc[i][0] + ba[n + 0];
        o.y = acc[i][1] + ba[n + 1];
        o.z = acc[i][2] + ba[n + 2];
        o.w = acc[i][3] + ba[n + 3];
        *(float4*)(att1 + (size_t)m * ATTD + n) = o;
    }
}

// ---------------- clspre = cls @ Wih[:,1024:1536]^T + bih + bhh ----------------
__global__ __launch_bounds__(256)
void clspre_kernel(const float* __restrict__ cls, const float* __restrict__ wih,
                   const float* __restrict__ bih, const float* __restrict__ bhh,
                   float* __restrict__ clspre) {
    __shared__ float As[16][68];
    __shared__ float Bs[16][68];
    int tid = threadIdx.x;
    int n0 = blockIdx.x * 64;
    int tx = tid & 15, ty = tid >> 4;
    int lm = tid >> 2, lk4 = (tid & 3) * 4;
    int bnn = tid & 63, bkk4 = (tid >> 6) * 4;
    float acc[4][4] = {};
    for (int k0 = 0; k0 < 512; k0 += 16) {
        float4 av = *(const float4*)(cls + lm * CLSE + k0 + lk4);
        float4 bv = *(const float4*)(wih + (size_t)(n0 + bnn) * XDIM + 1024 + k0 + bkk4);
        __syncthreads();
        As[lk4 + 0][lm] = av.x; As[lk4 + 1][lm] = av.y;
        As[lk4 + 2][lm] = av.z; As[lk4 + 3][lm] = av.w;
        Bs[bkk4 + 0][bnn] = bv.x; Bs[bkk4 + 1][bnn] = bv.y;
        Bs[bkk4 + 2][bnn] = bv.z; Bs[bkk4 + 3][bnn] = bv.w;
        __syncthreads();
#pragma unroll
        for (int kk = 0; kk < 16; kk++) {
            float4 a4 = *(const float4*)&As[kk][ty * 4];
            float4 b4 = *(const float4*)&Bs[kk][tx * 4];
            float a[4] = {a4.x, a4.y, a4.z, a4.w};
#pragma unroll
            for (int i = 0; i < 4; i++) {
                acc[i][0] = fmaf(a[i], b4.x, acc[i][0]);
                acc[i][1] = fmaf(a[i], b4.y, acc[i][1]);
                acc[i][2] = fmaf(a[i], b4.z, acc[i][2]);
                acc[i][3] = fmaf(a[i], b4.w, acc[i][3]);
            }
        }
    }
#pragma unroll
    for (int i = 0; i < 4; i++) {
        int m = ty * 4 + i;
#pragma unroll
        for (int jj = 0; jj < 4; jj++) {
            int n = n0 + tx * 4 + jj;
            clspre[m * G4 + n] = acc[i][jj] + bih[n] + bhh[n];
        }
    }
}

// ---------------- embpre: cpre2[t][b][gcol] = emb[caps[b,t]] @ Wih[:, :512]^T + clspre[b] ----
__global__ __launch_bounds__(256)
void embpre_kernel(const float* __restrict__ embW, const float* __restrict__ wih,
                   const float* __restrict__ clspreg, const int* __restrict__ caps_i,
                   float* __restrict__ cpre2) {
    __shared__ float As[16][68];
    __shared__ float Bs[16][68];
    int tid = threadIdx.x;
    int n0 = blockIdx.x * 64, t = blockIdx.y;
    int tx = tid & 15, ty = tid >> 4;
    int lm = tid >> 2, lk4 = (tid & 3) * 4;
    int bnn = tid & 63, bkk4 = (tid >> 6) * 4;
    const int cap = caps_i[lm * MAXLEN + t];
    const float* arow = embW + ((size_t)cap << 9);
    float acc[4][4] = {};
    for (int k0 = 0; k0 < 512; k0 += 16) {
        float4 av = *(const float4*)(arow + k0 + lk4);
        float4 bv = *(const float4*)(wih + (size_t)(n0 + bnn) * XDIM + k0 + bkk4);
        __syncthreads();
        As[lk4 + 0][lm] = av.x; As[lk4 + 1][lm] = av.y;
        As[lk4 + 2][lm] = av.z; As[lk4 + 3][lm] = av.w;
        Bs[bkk4 + 0][bnn] = bv.x; Bs[bkk4 + 1][bnn] = bv.y;
        Bs[bkk4 + 2][bnn] = bv.z; Bs[bkk4 + 3][bnn] = bv.w;
        __syncthreads();
#pragma unroll
        for (int kk = 0; kk < 16; kk++) {
            float4 a4 = *(const float4*)&As[kk][ty * 4];
            float4 b4 = *(const float4*)&Bs[kk][tx * 4];
            float a[4] = {a4.x, a4.y, a4.z, a4.w};
#pragma unroll
            for (int i = 0; i < 4; i++) {
                acc[i][0] = fmaf(a[i], b4.x, acc[i][0]);
                acc[i][1] = fmaf(a[i], b4.y, acc[i][1]);
                acc[i][2] = fmaf(a[i], b4.z, acc[i][2]);
                acc[i][3] = fmaf(a[i], b4.w, acc[i][3]);
            }
        }
    }
#pragma unroll
    for (int i = 0; i < 4; i++) {
        int bl = ty * 4 + i;
        int n = n0 + tx * 4;
        float4 cp = *(const float4*)&clspreg[bl * G4 + n];
        float4 o;
        o.x = acc[i][0] + cp.x; o.y = acc[i][1] + cp.y;
        o.z = acc[i][2] + cp.z; o.w = acc[i][3] + cp.w;
        *(float4*)&cpre2[((size_t)t * 64 + bl) * G4 + n] = o;
    }
}

// ================= persistent step-loop: flag-array barriers, resident weights =================
// 256 blocks x 256 thr (cooperative). Roles: attention (b=blk&63, q=blk>>6); gates (j=blk).
// No atomic-RMW barriers: producers publish epoch flags via plain relaxed stores after
// __syncthreads (vmcnt drain); waiters poll flags in parallel. h is ping-ponged.
template<int PRE>
__global__ __launch_bounds__(256)
void loop_kernel(const float* __restrict__ att1g, const float* __restrict__ encg,
                 const float* __restrict__ embW, const float* __restrict__ W2p,
                 const float* __restrict__ W3p, const float* __restrict__ cpreg,
                 const float* __restrict__ Wd, const float* __restrict__ Fb,
                 const float* __restrict__ dab, const float* __restrict__ fbb,
                 const float* __restrict__ fullw, const float* __restrict__ fullb,
                 const int* __restrict__ sortind, const int* __restrict__ declen,
                 const int* __restrict__ caps_i,
                 float* __restrict__ h1, float* __restrict__ h2,
                 const float* __restrict__ c0G, float* __restrict__ hall,
                 float* __restrict__ exch, float* __restrict__ paweG,
                 int* __restrict__ cntX, int* __restrict__ cntP,
                 int* __restrict__ aweflag, int* __restrict__ hflag,
                 float* __restrict__ aweG) {
    const int blk = blockIdx.x, tid = threadIdx.x;
    const int lane = tid & 63, wvid = tid >> 6;
    const int b = blk & 63, q = blk >> 6;
    const int d0 = blk * 2;
    constexpr int WST = PRE ? 516 : 1028;

    __shared__ float stage[64 * 132];
    __shared__ float W2res[8 * WST];
    __shared__ float W3res[8 * 516];
    __shared__ float hS[512];
    __shared__ float att2F[512];
    __shared__ float pa[256], pb[256];
    __shared__ float esS[52];
    __shared__ float redA[1], redB[1];
    __shared__ float pawe[4 * 520];
    __shared__ float Gs[8 * 66];
    __shared__ float CsS[64 * 8];
    __shared__ float cS[64 * 2];
    __shared__ float hRes[64 * 2];
    __shared__ int capS[64];
    __shared__ int declen_s[64];
    __shared__ int finS;

    // ---- one-time preamble: weights resident, c/h-own-slice resident ----
    if (PRE) {
        for (int idx = tid; idx < 1024; idx += 256) {
            int cc = idx >> 7, pos = (idx & 127) << 2;
            *(float4*)&W2res[cc * 516 + pos] =
                *(const float4*)&W2p[(size_t)blk * 8192 + cc * 1024 + 512 + pos];
        }
    } else {
        for (int idx = tid; idx < 2048; idx += 256) {
            int cc = idx >> 8, pos = (idx & 255) << 2;
            *(float4*)&W2res[cc * 1028 + pos] =
                *(const float4*)&W2p[(size_t)blk * 8192 + cc * 1024 + pos];
        }
    }
    for (int idx = tid; idx < 1024; idx += 256) {
        int cc = idx >> 7, pos = (idx & 127) << 2;
        *(float4*)&W3res[cc * 516 + pos] =
            *(const float4*)&W3p[(size_t)blk * 4096 + cc * 512 + pos];
    }
    if (!PRE) {
        for (int idx = tid; idx < 512; idx += 256) {
            int r = idx >> 3, cc = idx & 7;
            CsS[idx] = cpreg[(r << 11) + ((cc >> 1) << 9) + d0 + (cc & 1)];
        }
    }
    if (tid < 128) {
        int r = tid & 63, dd = tid >> 6;
        cS[r * 2 + dd] = c0G[r * 512 + d0 + dd];
        hRes[r * 2 + dd] = h1[r * 512 + d0 + dd];
    }
    if (tid < 64) declen_s[tid] = declen[tid];
    const int sb = sortind[b];
    __syncthreads();
    const int dlb = declen_s[b];

    for (int t = 0; t < MAXT; t++) {
        const float* hcur = (t & 1) ? h2 : h1;
        float* hnxt = (t & 1) ? h1 : h2;

        // ============ attention phase (roles b,q) ============
        if (t < dlb) {
            {
                double hv = cohLd((const double*)&hcur[b * 512 + 2 * tid]);
                *(double*)&hS[2 * tid] = hv;
            }
            __syncthreads();
            {
                const int c = tid & 127, kh = tid >> 7;
                const int col = 128 * q + c;
                const float* wd = Wd + (size_t)(kh << 8) * 512 + col;
                const float* fb = Fb + (size_t)(kh << 8) * 512 + col;
                const float* hp = hS + (kh << 8);
                float a2 = 0.f, fg = 0.f;
#pragma unroll 16
                for (int k = 0; k < 256; k++) {
                    float hv = hp[k];
                    a2 = fmaf(hv, wd[(size_t)k * 512], a2);
                    fg = fmaf(hv, fb[(size_t)k * 512], fg);
                }
                pa[tid] = a2; pb[tid] = fg;
            }
            __syncthreads();
            if (tid < 128) {
                int col = 128 * q + tid;
                cohStF(&exch[b * 1024 + col], pa[tid] + pa[tid + 128] + dab[col]);
                cohStF(&exch[b * 1024 + 512 + col], pb[tid] + pb[tid + 128] + fbb[col]);
            }
            __syncthreads();   // drain: slice at MALL before arrival
            if (tid == 0) {
                int* cx = &cntX[t * 64 + b];
                __hip_atomic_fetch_add(cx, 1, __ATOMIC_RELAXED, __HIP_MEMORY_SCOPE_AGENT);
                while (__hip_atomic_load(cx, __ATOMIC_RELAXED, __HIP_MEMORY_SCOPE_AGENT) < 4)
                    __builtin_amdgcn_s_sleep(2);
            }
            __syncthreads();
            att2F[tid] = cohLdF(&exch[b * 1024 + tid]);
            att2F[tid + 256] = cohLdF(&exch[b * 1024 + 256 + tid]);
            __syncthreads();

            const float fbv = fullb[0];
            {
                float4 t0 = *(const float4*)&att2F[lane * 8];
                float4 t1 = *(const float4*)&att2F[lane * 8 + 4];
                float4 w0 = *(const float4*)&fullw[lane * 8];
                float4 w1 = *(const float4*)&fullw[lane * 8 + 4];
                const float* a1b = att1g + (size_t)b * PP * 512;
                for (int lp = wvid; lp < 49; lp += 4) {
                    int p = 49 * q + lp;
                    const float4* ar = (const float4*)(a1b + (size_t)p * 512) + lane * 2;
                    float4 u0 = ar[0], u1 = ar[1];
                    float s = fmaxf(u0.x + t0.x, 0.f) * w0.x + fmaxf(u0.y + t0.y, 0.f) * w0.y
                            + fmaxf(u0.z + t0.z, 0.f) * w0.z + fmaxf(u0.w + t0.w, 0.f) * w0.w
                            + fmaxf(u1.x + t1.x, 0.f) * w1.x + fmaxf(u1.y + t1.y, 0.f) * w1.y
                            + fmaxf(u1.z + t1.z, 0.f) * w1.z + fmaxf(u1.w + t1.w, 0.f) * w1.w;
#pragma unroll
                    for (int off = 32; off; off >>= 1) s += __shfl_down(s, off, 64);
                    if (lane == 0) esS[lp] = s + fbv;
                }
            }
            __syncthreads();
            if (tid < 64) {
                float v = (tid < 49) ? esS[tid] : -1e30f;
#pragma unroll
                for (int off = 32; off; off >>= 1) v = fmaxf(v, __shfl_down(v, off, 64));
                if (tid == 0) redA[0] = v;
            }
            __syncthreads();
            const float mq = redA[0];
            if (tid < 64) {
                float ev = (tid < 49) ? expf(esS[tid] - mq) : 0.f;
                float sv = ev;
#pragma unroll
                for (int off = 32; off; off >>= 1) sv += __shfl_down(sv, off, 64);
                if (tid == 0) redB[0] = sv;
                if (tid < 49) esS[tid] = ev;
            }
            __syncthreads();
            const float Sq = redB[0];
            {
                float aw[8] = {};
                const float* encb = encg + (size_t)sb * PP * 512 + lane;
                for (int lp = wvid; lp < 49; lp += 4) {
                    int p = 49 * q + lp;
                    float al = esS[lp];
                    const float* ep = encb + (size_t)p * 512;
#pragma unroll
                    for (int i = 0; i < 8; i++) aw[i] = fmaf(al, ep[i << 6], aw[i]);
                }
#pragma unroll
                for (int i = 0; i < 8; i++) pawe[wvid * 520 + (i << 6) + lane] = aw[i];
            }
            __syncthreads();
            {
                const int k2 = 2 * tid;
                const int base = ((b << 2) + q) * 520;
                float s0 = pawe[k2] + pawe[520 + k2] + pawe[2 * 520 + k2] + pawe[3 * 520 + k2];
                float s1 = pawe[k2 + 1] + pawe[520 + k2 + 1] + pawe[2 * 520 + k2 + 1] + pawe[3 * 520 + k2 + 1];
                double d;
                *(float2*)&d = make_float2(s0, s1);
                cohSt((double*)&paweG[base + k2], d);
                if (tid == 0) {
                    cohStF(&paweG[base + 512], Sq);
                    cohStF(&paweG[base + 513], mq);
                }
            }
            __syncthreads();   // drain: partials at MALL before arrival
            if (tid == 0) {
                int prev = __hip_atomic_fetch_add(&cntP[t * 64 + b], 1,
                                                  __ATOMIC_RELAXED, __HIP_MEMORY_SCOPE_AGENT);
                finS = (prev == 3);
            }
            __syncthreads();
            if (finS) {
                float mv[4], sv[4];
#pragma unroll
                for (int qq = 0; qq < 4; qq++) {
                    mv[qq] = cohLdF(&paweG[((b << 2) + qq) * 520 + 513]);
                    sv[qq] = cohLdF(&paweG[((b << 2) + qq) * 520 + 512]);
                }
                float M = fmaxf(fmaxf(mv[0], mv[1]), fmaxf(mv[2], mv[3]));
                float f0 = expf(mv[0] - M), f1 = expf(mv[1] - M);
                float f2 = expf(mv[2] - M), f3 = expf(mv[3] - M);
                float inv = 1.f / (sv[0] * f0 + sv[1] * f1 + sv[2] * f2 + sv[3] * f3);
                const int k2 = 2 * tid;
                const double* pd = (const double*)paweG;
                float a0, a1;
                {
                    double dv0 = cohLd(pd + ((b << 2) + 0) * 260 + tid);
                    double dv1 = cohLd(pd + ((b << 2) + 1) * 260 + tid);
                    double dv2 = cohLd(pd + ((b << 2) + 2) * 260 + tid);
                    double dv3 = cohLd(pd + ((b << 2) + 3) * 260 + tid);
                    float2 g0 = *(float2*)&dv0, g1 = *(float2*)&dv1;
                    float2 g2 = *(float2*)&dv2, g3 = *(float2*)&dv3;
                    a0 = g0.x * f0 + g1.x * f1 + g2.x * f2 + g3.x * f3;
                    a1 = g0.y * f0 + g1.y * f1 + g2.y * f2 + g3.y * f3;
                }
                double gpair = cohLd((const double*)&exch[b * 1024 + 512 + k2]);
                float2 g2v = *(float2*)&gpair;
                double st;
                *(float2*)&st = make_float2(a0 * inv * sigm(g2v.x), a1 * inv * sigm(g2v.y));
                cohSt((double*)&aweG[b * 512 + k2], st);
            }
            __syncthreads();   // drain finalizer's awe stores
            if (finS && tid == 0) cohStI(&aweflag[b], t + 1);
        }

        // ============ gate phase (role j=blk) ============
        if (PRE) {
            const float* cp = cpreg + (size_t)t * 64 * G4;
            for (int idx = tid; idx < 512; idx += 256) {
                int r = idx >> 3, cc = idx & 7;
                CsS[idx] = cp[(r << 11) + ((cc >> 1) << 9) + d0 + (cc & 1)];
            }
        } else if (tid < 64) {
            capS[tid] = caps_i[tid * MAXLEN + t];
        }

        float ac0 = 0.f, ac1 = 0.f;

        // --- emb chunks (non-PRE only; awe-independent) ---
        if (!PRE) {
            __syncthreads();   // capS ready
            for (int ch = 0; ch < 4; ch++) {
                __syncthreads();
                {
                    const float4* src = (const float4*)(embW + ((size_t)capS[lane] << 9) + (ch << 7) + (wvid << 5));
                    float4 tmp[8];
#pragma unroll
                    for (int i = 0; i < 8; i++) tmp[i] = src[i];
#pragma unroll
                    for (int i = 0; i < 8; i++)
                        *(float4*)&stage[lane * 132 + (wvid << 5) + (i << 2)] = tmp[i];
                }
                __syncthreads();
                const float* sp = &stage[lane * 132];
                const float* v0p = &W2res[wvid * WST + (ch << 7)];
                const float* v1p = &W2res[(wvid + 4) * WST + (ch << 7)];
#pragma unroll 8
                for (int kk = 0; kk < 128; kk += 4) {
                    float4 av = *(const float4*)(sp + kk);
                    float4 u0 = *(const float4*)(v0p + kk);
                    float4 u1 = *(const float4*)(v1p + kk);
                    ac0 = fmaf(av.x, u0.x, fmaf(av.y, u0.y, fmaf(av.z, u0.z, fmaf(av.w, u0.w, ac0))));
                    ac1 = fmaf(av.x, u1.x, fmaf(av.y, u1.y, fmaf(av.z, u1.z, fmaf(av.w, u1.w, ac1))));
                }
            }
        }

        // --- h chunks (awe-independent; coh + register prefetch) ---
        {
            double tmp[16];
            {
                const double* ap = (const double*)(hcur + ((size_t)lane << 9) + (wvid << 5));
#pragma unroll
                for (int i = 0; i < 16; i++) tmp[i] = cohLd(ap + i);
            }
            for (int ch = 0; ch < 4; ch++) {
                __syncthreads();
#pragma unroll
                for (int i = 0; i < 8; i++) {
                    float2 fa = *(float2*)&tmp[2 * i], fb2 = *(float2*)&tmp[2 * i + 1];
                    *(float4*)&stage[lane * 132 + (wvid << 5) + (i << 2)] =
                        make_float4(fa.x, fa.y, fb2.x, fb2.y);
                }
                __syncthreads();
                if (ch < 3) {
                    const double* ap = (const double*)(hcur + ((size_t)lane << 9) + ((ch + 1) << 7) + (wvid << 5));
#pragma unroll
                    for (int i = 0; i < 16; i++) tmp[i] = cohLd(ap + i);
                }
                const float* sp = &stage[lane * 132];
                const float* v0p = &W3res[wvid * 516 + (ch << 7)];
                const float* v1p = &W3res[(wvid + 4) * 516 + (ch << 7)];
#pragma unroll 8
                for (int kk = 0; kk < 128; kk += 4) {
                    float4 av = *(const float4*)(sp + kk);
                    float4 u0 = *(const float4*)(v0p + kk);
                    float4 u1 = *(const float4*)(v1p + kk);
                    ac0 = fmaf(av.x, u0.x, fmaf(av.y, u0.y, fmaf(av.z, u0.z, fmaf(av.w, u0.w, ac0))));
                    ac1 = fmaf(av.x, u1.x, fmaf(av.y, u1.y, fmaf(av.z, u1.z, fmaf(av.w, u1.w, ac1))));
                }
            }
        }

        // --- barrier W: awe ready for all active batches (flag-array poll) ---
        if (tid < 64) {
            while (!(t >= declen_s[tid] || cohLdI(&aweflag[tid]) > t))
                __builtin_amdgcn_s_sleep(2);
        }
        __syncthreads();

        // --- awe chunks (coh + register prefetch) ---
        {
            double tmp[16];
            {
                const double* ap = (const double*)(aweG + ((size_t)lane << 9) + (wvid << 5));
#pragma unroll
                for (int i = 0; i < 16; i++) tmp[i] = cohLd(ap + i);
            }
            for (int ch = 0; ch < 4; ch++) {
                __syncthreads();
#pragma unroll
                for (int i = 0; i < 8; i++) {
                    float2 fa = *(float2*)&tmp[2 * i], fb2 = *(float2*)&tmp[2 * i + 1];
                    *(float4*)&stage[lane * 132 + (wvid << 5) + (i << 2)] =
                        make_float4(fa.x, fa.y, fb2.x, fb2.y);
                }
                __syncthreads();
                if (ch < 3) {
                    const double* ap = (const double*)(aweG + ((size_t)lane << 9) + ((ch + 1) << 7) + (wvid << 5));
#pragma unroll
                    for (int i = 0; i < 16; i++) tmp[i] = cohLd(ap + i);
                }
                const float* sp = &stage[lane * 132];
                const int off = PRE ? (ch << 7) : (512 + (ch << 7));
                const float* v0p = &W2res[wvid * WST + off];
                const float* v1p = &W2res[(wvid + 4) * WST + off];
#pragma unroll 8
                for (int kk = 0; kk < 128; kk += 4) {
                    float4 av = *(const float4*)(sp + kk);
                    float4 u0 = *(const float4*)(v0p + kk);
                    float4 u1 = *(const float4*)(v1p + kk);
                    ac0 = fmaf(av.x, u0.x, fmaf(av.y, u0.y, fmaf(av.z, u0.z, fmaf(av.w, u0.w, ac0))));
                    ac1 = fmaf(av.x, u1.x, fmaf(av.y, u1.y, fmaf(av.z, u1.z, fmaf(av.w, u1.w, ac1))));
                }
            }
        }

        // --- LSTM update (c, own-h resident in LDS) ---
        Gs[wvid * 66 + lane]       = ac0 + CsS[(lane << 3) + wvid];
        Gs[(wvid + 4) * 66 + lane] = ac1 + CsS[(lane << 3) + wvid + 4];
        __syncthreads();
        if (tid < 128) {
            int r2 = tid & 63, dd = tid >> 6;
            if (t < declen_s[r2]) {
                float iv = Gs[(0 + dd) * 66 + r2];
                float fv = Gs[(2 + dd) * 66 + r2];
                float gv = Gs[(4 + dd) * 66 + r2];
                float ov = Gs[(6 + dd) * 66 + r2];
                float cold = cS[r2 * 2 + dd];
                float cn = sigm(fv) * cold + sigm(iv) * tanhf(gv);
                float hn = sigm(ov) * tanhf(cn);
                cS[r2 * 2 + dd] = cn;
                hRes[r2 * 2 + dd] = hn;
            }
        }
        __syncthreads();
        if (tid < 64) {
            double hv2 = *(double*)&hRes[tid * 2];
            cohSt((double*)&hnxt[tid * 512 + d0], hv2);
            if (t < declen_s[tid])
                *(double*)&hall[((size_t)tid * MAXT + t) * 512 + d0] = hv2;
        }
        __syncthreads();   // drain h stores before flag
        if (tid == 0) cohStI(&hflag[blk], t + 1);

        // --- barrier H: all blocks' h(t) published (flag-array poll) ---
        while (cohLdI(&hflag[tid]) <= t)
            __builtin_amdgcn_s_sleep(2);
        __syncthreads();
    }
}

// ---------------- FC: 3264x10000, K=512 — 64x128 tile, split-half B reads ----------------
__global__ __launch_bounds__(256)
void fc_kernel(const float* __restrict__ hall, const float* __restrict__ fcW,
               const float* __restrict__ fcb, const int* __restrict__ declen,
               float* __restrict__ out) {
    __shared__ float As[16][68];
    __shared__ float Bs[16][132];
    int tid = threadIdx.x;
    int n0 = blockIdx.x * 128, m0 = blockIdx.y * 64;
    int tx = tid & 15, ty = tid >> 4;
    int lm = tid >> 2, lk4 = (tid & 3) * 4;
    int bkk = tid >> 4, bnn8 = (tid & 15) * 8;
    const float* arow = hall + (size_t)(m0 + lm) * DECD;
    bool nfull = (n0 + 128 <= VOC);
    float acc[4][8] = {};
    for (int k0 = 0; k0 < 512; k0 += 16) {
        float4 av = *(const float4*)(arow + k0 + lk4);
        float4 bv0, bv1;
        const float* bp = fcW + (size_t)(k0 + bkk) * VOC;
        if (nfull) {
            bv0 = *(const float4*)(bp + n0 + bnn8);
            bv1 = *(const float4*)(bp + n0 + bnn8 + 4);
        } else {
            int nb = n0 + bnn8;
            float tv[8];
#pragma unroll
            for (int u = 0; u < 8; u++) tv[u] = (nb + u < VOC) ? bp[nb + u] : 0.f;
            bv0 = make_float4(tv[0], tv[1], tv[2], tv[3]);
            bv1 = make_float4(tv[4], tv[5], tv[6], tv[7]);
        }
        __syncthreads();
        As[lk4 + 0][lm] = av.x; As[lk4 + 1][lm] = av.y;
        As[lk4 + 2][lm] = av.z; As[lk4 + 3][lm] = av.w;
        *(float4*)&Bs[bkk][bnn8] = bv0;
        *(float4*)&Bs[bkk][bnn8 + 4] = bv1;
        __syncthreads();
#pragma unroll
        for (int kk = 0; kk < 16; kk++) {
            float4 a4 = *(const float4*)&As[kk][ty * 4];
            float4 b40 = *(const float4*)&Bs[kk][tx * 4];        // cols [0,64)
            float4 b41 = *(const float4*)&Bs[kk][64 + tx * 4];   // cols [64,128)
            float a[4] = {a4.x, a4.y, a4.z, a4.w};
#pragma unroll
            for (int i = 0; i < 4; i++) {
                acc[i][0] = fmaf(a[i], b40.x, acc[i][0]);
                acc[i][1] = fmaf(a[i], b40.y, acc[i][1]);
                acc[i][2] = fmaf(a[i], b40.z, acc[i][2]);
                acc[i][3] = fmaf(a[i], b40.w, acc[i][3]);
                acc[i][4] = fmaf(a[i], b41.x, acc[i][4]);
                acc[i][5] = fmaf(a[i], b41.y, acc[i][5]);
                acc[i][6] = fmaf(a[i], b41.z, acc[i][6]);
                acc[i][7] = fmaf(a[i], b41.w, acc[i][7]);
            }
        }
    }
#pragma unroll
    for (int i = 0; i < 4; i++) {
        int m = m0 + ty * 4 + i;
        int bq = m / MAXT, tq = m - bq * MAXT;
        bool act = tq < declen[bq];
        int nlo = n0 + tx * 4, nhi = n0 + 64 + tx * 4;
        if (nfull) {
            float4 o0, o1;
            o0.x = act ? acc[i][0] + fcb[nlo + 0] : 0.f;
            o0.y = act ? acc[i][1] + fcb[nlo + 1] : 0.f;
            o0.z = act ? acc[i][2] + fcb[nlo + 2] : 0.f;
            o0.w = act ? acc[i][3] + fcb[nlo + 3] : 0.f;
            o1.x = act ? acc[i][4] + fcb[nhi + 0] : 0.f;
            o1.y = act ? acc[i][5] + fcb[nhi + 1] : 0.f;
            o1.z = act ? acc[i][6] + fcb[nhi + 2] : 0.f;
            o1.w = act ? acc[i][7] + fcb[nhi + 3] : 0.f;
            *(float4*)(out + (size_t)m * VOC + nlo) = o0;
            *(float4*)(out + (size_t)m * VOC + nhi) = o1;
        } else {
#pragma unroll
            for (int jj = 0; jj < 4; jj++) {
                int nn = nlo + jj;
                if (nn < VOC) out[(size_t)m * VOC + nn] = act ? acc[i][jj] + fcb[nn] : 0.f;
            }
#pragma unroll
            for (int jj = 0; jj < 4; jj++) {
                int nn = nhi + jj;
                if (nn < VOC) out[(size_t)m * VOC + nn] = act ? acc[i][4 + jj] + fcb[nn] : 0.f;
            }
        }
    }
}

extern "C" void kernel_launch(void* const* d_in, const int* in_sizes, int n_in,
                              void* d_out, int out_size, void* d_ws, size_t ws_size,
                              hipStream_t stream) {
    const float* enc     = (const float*)d_in[0];
    const int*   ecaps   = (const int*)d_in[1];
    const int*   lens    = (const int*)d_in[2];
    const int*   classk  = (const int*)d_in[3];
    const float* embW    = (const float*)d_in[4];
    const float* clsW    = (const float*)d_in[5];
    const float* encattW = (const float*)d_in[6];
    const float* encattb = (const float*)d_in[7];
    const float* decattW = (const float*)d_in[8];
    const float* decattb = (const float*)d_in[9];
    const float* fullw   = (const float*)d_in[10];
    const float* fullb   = (const float*)d_in[11];
    const float* ihW     = (const float*)d_in[12];
    const float* ihb     = (const float*)d_in[13];
    const float* icW     = (const float*)d_in[14];
    const float* icb     = (const float*)d_in[15];
    const float* fbW     = (const float*)d_in[16];
    const float* fbb     = (const float*)d_in[17];
    const float* Wih     = (const float*)d_in[18];
    const float* Whh     = (const float*)d_in[19];
    const float* bih     = (const float*)d_in[20];
    const float* bhh     = (const float*)d_in[21];
    const float* fcW     = (const float*)d_in[22];
    const float* fcb     = (const float*)d_in[23];

    float* out = (float*)d_out;
    float* ws  = (float*)d_ws;
    int*   wsi = (int*)d_ws;

    int*   sortind = wsi + W_SORT;
    int*   declen  = wsi + W_DECLEN;
    int*   caps_i  = wsi + W_CAPS;
    int*   cntP    = wsi + W_CNTP;
    int*   cntX    = wsi + W_CNTX;
    int*   aweflag = wsi + W_AWEF;
    int*   hflag   = wsi + W_HFLG;
    float* cls     = ws + W_CLS;
    float* h1      = ws + W_H;
    float* h2      = ws + W_H2;
    float* c       = ws + W_C;
    float* initin  = ws + W_ININ;
    float* exch    = ws + W_EXCH;
    float* awe     = ws + W_AWE;
    float* clspre  = ws + W_CLSPRE;
    float* W3p     = ws + W_W3P;
    float* W2p     = ws + W_W2P;
    float* hall    = ws + W_HALL;
    float* att1    = ws + W_ATT1;
    float* pawe    = ws + W_PAWE;
    float* cpre2   = ws + W_CPRE2;

    const bool pre = ws_size >= W_END * 4;   // cpre2 fits in workspace?

    setup_kernel<<<1, 64, 0, stream>>>(lens, out, sortind, declen, cntP);
    gather_kernel<<<141, 256, 0, stream>>>(ecaps, classk, clsW, sortind, caps_i, cls, out);
    mean_cls_kernel<<<BB, 256, 0, stream>>>(enc, cls, sortind, initin);
    init_hc_kernel<<<256, 256, 0, stream>>>(initin, ihW, ihb, icW, icb, h1, c);
    pack_w2p_kernel<<<8192, 256, 0, stream>>>(Wih, W2p);
    pack_w3p_kernel<<<4096, 256, 0, stream>>>(Whh, W3p);
    att1_kernel<<<dim3(8, 196), 256, 0, stream>>>(enc, encattW, encattb, sortind, att1);
    clspre_kernel<<<32, 256, 0, stream>>>(cls, Wih, bih, bhh, clspre);
    if (pre)
        embpre_kernel<<<dim3(32, 51), 256, 0, stream>>>(embW, Wih, clspre, caps_i, cpre2);

    const float* cpreArg = pre ? cpre2 : clspre;
    void* kargs[] = {
        (void*)&att1, (void*)&enc, (void*)&embW, (void*)&W2p, (void*)&W3p,
        (void*)&cpreArg, (void*)&decattW, (void*)&fbW, (void*)&decattb, (void*)&fbb,
        (void*)&fullw, (void*)&fullb, (void*)&sortind, (void*)&declen, (void*)&caps_i,
        (void*)&h1, (void*)&h2, (void*)&c, (void*)&hall, (void*)&exch, (void*)&pawe,
        (void*)&cntX, (void*)&cntP, (void*)&aweflag, (void*)&hflag, (void*)&awe
    };
    hipLaunchCooperativeKernel(pre ? (const void*)loop_kernel<1>
                                   : (const void*)loop_kernel<0>,
                               dim3(256), dim3(256), kargs, 0, stream);

    fc_kernel<<<dim3(79, 51), 256, 0, stream>>>(hall, fcW, fcb, declen, out);
}